// Round 2
// baseline (254.598 us; speedup 1.0000x reference)
//
#include <hip/hip_runtime.h>

typedef float nf4 __attribute__((ext_vector_type(4)));

// Cell2Tissue: conv3x3(cell) -> avgpool4 -> add into per-sample ROI of tissue -> broadcast x4.
//
// Pipeline:
//  k_wtrans : w[c][ci][3][3] -> wT[ci][c][9]            (coalesced wT writes)
//  k_box    : box[ci][yy][xx] = 4x4 box-sum of zero-padded cell (only rows yy%4!=3 needed)
//  k_gemm   : part[s][c][i*64+j] = sum_{ci in split s} sum_k wT[ci][c][k]*box[ci][4i+dy][4j+dx]
//  k_avgfin : avg = bias + (sum_s part[s]) / 16
//  k_out    : out[b][j][c][h][w] = tissue[j][c][h][w] + (in ROI_j ? avg[...] : 0), b=0..3
//
// ws layout (bytes): box @0 (33,554,432) | wT @33,554,432 (589,824) |
//                    part @34,144,256 (16,777,216) | avg @50,921,472 (2,097,152)
// total ws need ~53 MB.

__global__ __launch_bounds__(256) void k_wtrans(const float* __restrict__ w,
                                                float* __restrict__ wT) {
    int idx = blockIdx.x * 256 + threadIdx.x;          // enumerates wT linearly, 147456
    if (idx >= 128 * 128 * 9) return;
    int k  = idx % 9;
    int c  = (idx / 9) % 128;
    int ci = idx / (9 * 128);
    wT[idx] = w[(c * 128 + ci) * 9 + k];
}

// box[ci][yy][xx] = sum_{p,q<4} cellpad[ci][yy-1+p][xx-1+q], zero pad outside [0,256)
// Only yy in {4i, 4i+1, 4i+2} are consumed -> compute 192 of 256 rows.
__global__ __launch_bounds__(256) void k_box(const float* __restrict__ cell,
                                             float* __restrict__ box) {
    int idx = blockIdx.x * 256 + threadIdx.x;          // 128 * 192 * 64 = 1,572,864
    int xt = idx & 63;
    int t  = idx >> 6;
    int yr = t % 192;
    int ci = t / 192;
    int yy = (yr / 3) * 4 + (yr % 3);                  // skips yy%4==3
    int x0 = xt * 4;
    const float* base = cell + (size_t)ci * 65536;

    float v[12];
#pragma unroll
    for (int i = 0; i < 12; ++i) v[i] = 0.f;

#pragma unroll
    for (int p = 0; p < 4; ++p) {
        int row = yy - 1 + p;
        if (row < 0 || row > 255) continue;
        const float* rp = base + row * 256;
        if (x0 >= 4) {
            float4 a = *(const float4*)(rp + x0 - 4);
            v[0] += a.x; v[1] += a.y; v[2] += a.z; v[3] += a.w;
        }
        float4 b = *(const float4*)(rp + x0);
        v[4] += b.x; v[5] += b.y; v[6] += b.z; v[7] += b.w;
        if (x0 + 4 < 256) {
            float4 c4 = *(const float4*)(rp + x0 + 4);
            v[8] += c4.x; v[9] += c4.y; v[10] += c4.z; v[11] += c4.w;
        }
    }
    // v[i] holds vertical sum of column x0-4+i ; box col (x0+t) sums cols x0+t-1 .. x0+t+2
    float4 o;
    o.x = v[3] + v[4] + v[5] + v[6];
    o.y = v[4] + v[5] + v[6] + v[7];
    o.z = v[5] + v[6] + v[7] + v[8];
    o.w = v[6] + v[7] + v[8] + v[9];
    *(float4*)(box + (size_t)ci * 65536 + yy * 256 + x0) = o;
}

// grid (64 tiles, 8 K-splits), 256 threads.
// lanes = 8x8 pooled positions; wave w handles out-channels [w*32, w*32+32).
__global__ __launch_bounds__(256) void k_gemm(const float* __restrict__ box,
                                              const float* __restrict__ wT,
                                              float* __restrict__ part) {
    __shared__ float bs[31 * 34];                      // stride 34 -> 2-way bank alias (free)
    int tile  = blockIdx.x;                            // 0..63
    int split = blockIdx.y;                            // 0..7
    int ti = tile >> 3, tj = tile & 7;
    int tid  = threadIdx.x;
    int lane = tid & 63;
    int wv   = tid >> 6;                               // 0..3
    int ii = lane >> 3, jj = lane & 7;                 // position within 8x8 tile
    int cbase = wv * 32;
    int yy0 = ti * 32, xx0 = tj * 32;

    float acc[32];
#pragma unroll
    for (int m = 0; m < 32; ++m) acc[m] = 0.f;

    for (int t = 0; t < 16; ++t) {
        int ci = split * 16 + t;
        __syncthreads();
        const float* src = box + (size_t)ci * 65536;
        for (int s = tid; s < 992; s += 256) {         // stage 31x32 box tile
            int r = s >> 5, cl = s & 31;
            bs[r * 34 + cl] = src[(yy0 + r) * 256 + xx0 + cl];
        }
        __syncthreads();

        float bx[9];
#pragma unroll
        for (int dy = 0; dy < 3; ++dy)
#pragma unroll
            for (int dx = 0; dx < 3; ++dx)
                bx[dy * 3 + dx] = bs[(4 * ii + dy) * 34 + 4 * jj + dx];

        const float* wci = wT + ((size_t)ci * 128 + cbase) * 9;   // wave-uniform -> s_load
#pragma unroll
        for (int m = 0; m < 32; ++m) {
#pragma unroll
            for (int k = 0; k < 9; ++k)
                acc[m] = fmaf(wci[m * 9 + k], bx[k], acc[m]);
        }
    }

    float* dst = part + (size_t)split * (128 * 4096);
    int pos = (ti * 8 + ii) * 64 + (tj * 8 + jj);
#pragma unroll
    for (int m = 0; m < 32; ++m)
        dst[(cbase + m) * 4096 + pos] = acc[m];
}

__global__ __launch_bounds__(256) void k_avgfin(const float* __restrict__ part,
                                                const float* __restrict__ bias,
                                                float* __restrict__ avg) {
    int idx = blockIdx.x * 256 + threadIdx.x;          // < 524288
    int c = idx >> 12;
    float s = 0.f;
#pragma unroll
    for (int sp = 0; sp < 8; ++sp) s += part[sp * 524288 + idx];
    avg[idx] = bias[c] + s * 0.0625f;
}

__global__ __launch_bounds__(256) void k_out(const float* __restrict__ tissue,
                                             const float* __restrict__ avg,
                                             const int* __restrict__ loc,
                                             float* __restrict__ out) {
    int idx4 = blockIdx.x * 256 + threadIdx.x;         // < 8,388,608 float4s of `final`
    size_t f = (size_t)idx4 * 4;
    int j   = idx4 >> 21;                              // sample (2^21 float4 per sample)
    int r4  = idx4 & ((1 << 21) - 1);
    int c   = r4 >> 14;                                // 16384 float4 per channel
    int hw4 = r4 & 16383;
    int h   = hw4 >> 6;                                // 64 float4 per row
    int w0  = (hw4 & 63) << 2;

    float4 v = *(const float4*)(tissue + f);

    // axis-1 (h) uses loc[:,1]; axis-2 (w) uses loc[:,0]; start = loc/4 - 32
    int sh = (loc[2 * j + 1] >> 2) - 32;
    int sw = (loc[2 * j]     >> 2) - 32;
    int ah = h - sh;
    if (ah >= 0 && ah < 64) {
        const float* ar = avg + c * 4096 + ah * 64;
        int aw = w0 - sw;
        if (aw     >= 0 && aw     < 64) v.x += ar[aw];
        if (aw + 1 >= 0 && aw + 1 < 64) v.y += ar[aw + 1];
        if (aw + 2 >= 0 && aw + 2 < 64) v.z += ar[aw + 2];
        if (aw + 3 >= 0 && aw + 3 < 64) v.w += ar[aw + 3];
    }
    nf4 nv = *(nf4*)&v;
#pragma unroll
    for (int b = 0; b < 4; ++b)
        __builtin_nontemporal_store(nv, (nf4*)(out + (size_t)b * 33554432 + f));
}

extern "C" void kernel_launch(void* const* d_in, const int* in_sizes, int n_in,
                              void* d_out, int out_size, void* d_ws, size_t ws_size,
                              hipStream_t stream) {
    const float* tissue = (const float*)d_in[0];
    const float* cell   = (const float*)d_in[1];
    const int*   loc    = (const int*)d_in[2];
    const float* w      = (const float*)d_in[3];
    const float* bias   = (const float*)d_in[4];
    float* out = (float*)d_out;

    char* wsb = (char*)d_ws;
    float* box  = (float*)(wsb);
    float* wT   = (float*)(wsb + 33554432);
    float* part = (float*)(wsb + 34144256);
    float* avg  = (float*)(wsb + 50921472);

    k_wtrans<<<576, 256, 0, stream>>>(w, wT);
    k_box<<<6144, 256, 0, stream>>>(cell, box);
    k_gemm<<<dim3(64, 8), 256, 0, stream>>>(box, wT, part);
    k_avgfin<<<2048, 256, 0, stream>>>(part, bias, avg);
    k_out<<<32768, 256, 0, stream>>>(tissue, avg, loc, out);
}

// Round 3
// 182.826 us; speedup vs baseline: 1.3926x; 1.3926x over previous
//
#include <hip/hip_runtime.h>

typedef float nf4 __attribute__((ext_vector_type(4)));

// Cell2Tissue: conv3x3(cell) -> avgpool4 -> add into per-sample ROI of tissue -> broadcast x4.
//
// Pipeline:
//  k_prep   : (fused) wT2[ci][k][c] transpose + box = 4x4 box-sum of zero-padded cell
//  k_gemm   : part[s][c][i*64+j] = sum_{ci in split s} sum_k wT2[ci][k][c]*box[ci][4i+dy][4j+dx]
//             lanes = out-channels (coalesced/vector weight path), box via LDS broadcast
//  k_avgfin : avg = bias + (sum_s part[s]) / 16
//  k_out    : out[b][j][c][h][w] = tissue[j][c][h][w] + (in ROI_j ? avg[...] : 0), b=0..3
//
// ws layout (bytes): box @0 (33,554,432) | wT2 @33,554,432 (589,824) |
//                    part @34,144,256 (16,777,216) | avg @50,921,472 (2,097,152)

// ---- fused prep: blocks [0,576) transpose weights, blocks [576, 6720) box-sum ----
__global__ __launch_bounds__(256) void k_prep(const float* __restrict__ w,
                                              float* __restrict__ wT2,
                                              const float* __restrict__ cell,
                                              float* __restrict__ box) {
    if (blockIdx.x < 576) {
        int idx = blockIdx.x * 256 + threadIdx.x;      // enumerates wT2 linearly, 147456
        int c  = idx & 127;
        int k  = (idx >> 7) % 9;
        int ci = idx / (9 * 128);
        wT2[idx] = w[(c * 128 + ci) * 9 + k];
        return;
    }
    // box[ci][yy][xx] = sum_{p,q<4} cellpad[ci][yy-1+p][xx-1+q]; only yy%4 in {0,1,2} needed
    int idx = (blockIdx.x - 576) * 256 + threadIdx.x;  // 128 * 192 * 64 = 1,572,864
    int xt = idx & 63;
    int t  = idx >> 6;
    int yr = t % 192;
    int ci = t / 192;
    int yy = (yr / 3) * 4 + (yr % 3);                  // skips yy%4==3
    int x0 = xt * 4;
    const float* base = cell + (size_t)ci * 65536;

    float v[12];
#pragma unroll
    for (int i = 0; i < 12; ++i) v[i] = 0.f;

#pragma unroll
    for (int p = 0; p < 4; ++p) {
        int row = yy - 1 + p;
        if (row < 0 || row > 255) continue;
        const float* rp = base + row * 256;
        if (x0 >= 4) {
            float4 a = *(const float4*)(rp + x0 - 4);
            v[0] += a.x; v[1] += a.y; v[2] += a.z; v[3] += a.w;
        }
        float4 b = *(const float4*)(rp + x0);
        v[4] += b.x; v[5] += b.y; v[6] += b.z; v[7] += b.w;
        if (x0 + 4 < 256) {
            float4 c4 = *(const float4*)(rp + x0 + 4);
            v[8] += c4.x; v[9] += c4.y; v[10] += c4.z; v[11] += c4.w;
        }
    }
    float4 o;
    o.x = v[3] + v[4] + v[5] + v[6];
    o.y = v[4] + v[5] + v[6] + v[7];
    o.z = v[5] + v[6] + v[7] + v[8];
    o.w = v[6] + v[7] + v[8] + v[9];
    *(float4*)(box + (size_t)ci * 65536 + yy * 256 + x0) = o;
}

// grid (64 rows, 8 K-splits), 256 threads. Lane = channel group (4 c), pg = 8 positions.
// All weight reads: coalesced global -> LDS -> ds_read_b128 (no scalar-promotion reliance).
// All box reads: LDS broadcast (same addr across half-wave) -> free.
__global__ __launch_bounds__(256) void k_gemm(const float* __restrict__ box,
                                              const float* __restrict__ wT2,
                                              float* __restrict__ part) {
    __shared__ float wlds[2][1152];                    // [buf][k*128 + c]
    __shared__ float boxlds[2][768];                   // [buf][dy*256 + x]
    int i     = blockIdx.x;                            // pooled row 0..63
    int split = blockIdx.y;                            // 0..7
    int tid = threadIdx.x;
    int cg  = tid & 31;                                // c = 4*cg .. 4*cg+3
    int pg  = tid >> 5;                                // j = 8*pg .. 8*pg+7

    float acc[4][8];
#pragma unroll
    for (int a = 0; a < 4; ++a)
#pragma unroll
        for (int p = 0; p < 8; ++p) acc[a][p] = 0.f;

    int ci0 = split * 16;

    // stage ci into buf
    auto stage = [&](int ci, int buf) {
        const float* bsrc = box + (size_t)ci * 65536 + (4 * i) * 256;  // rows 4i..4i+2 contiguous
#pragma unroll
        for (int s = 0; s < 3; ++s)
            boxlds[buf][tid + 256 * s] = bsrc[tid + 256 * s];
        const float* wsrc = wT2 + (size_t)ci * 1152;
#pragma unroll
        for (int s = 0; s < 5; ++s) {
            int q = tid + 256 * s;
            if (q < 1152) wlds[buf][q] = wsrc[q];
        }
    };

    stage(ci0, 0);
    for (int t = 0; t < 16; ++t) {
        __syncthreads();
        if (t < 15) stage(ci0 + t + 1, (t + 1) & 1);
        int b = t & 1;

        nf4 wv[9];
#pragma unroll
        for (int k = 0; k < 9; ++k)
            wv[k] = *(const nf4*)&wlds[b][k * 128 + 4 * cg];

#pragma unroll
        for (int p = 0; p < 8; ++p) {
            int j = 8 * pg + p;
            nf4 b0 = *(const nf4*)&boxlds[b][0 * 256 + 4 * j];
            nf4 b1 = *(const nf4*)&boxlds[b][1 * 256 + 4 * j];
            nf4 b2 = *(const nf4*)&boxlds[b][2 * 256 + 4 * j];
#pragma unroll
            for (int a = 0; a < 4; ++a) {
                float s = acc[a][p];
                s = fmaf(wv[0][a], b0[0], s);
                s = fmaf(wv[1][a], b0[1], s);
                s = fmaf(wv[2][a], b0[2], s);
                s = fmaf(wv[3][a], b1[0], s);
                s = fmaf(wv[4][a], b1[1], s);
                s = fmaf(wv[5][a], b1[2], s);
                s = fmaf(wv[6][a], b2[0], s);
                s = fmaf(wv[7][a], b2[1], s);
                s = fmaf(wv[8][a], b2[2], s);
                acc[a][p] = s;
            }
        }
    }

    float* dst = part + (size_t)split * (128 * 4096);
#pragma unroll
    for (int a = 0; a < 4; ++a) {
        int c = 4 * cg + a;
        float* row = dst + (size_t)c * 4096 + i * 64 + 8 * pg;
        float4 lo = make_float4(acc[a][0], acc[a][1], acc[a][2], acc[a][3]);
        float4 hi = make_float4(acc[a][4], acc[a][5], acc[a][6], acc[a][7]);
        *(float4*)(row)     = lo;
        *(float4*)(row + 4) = hi;
    }
}

__global__ __launch_bounds__(256) void k_avgfin(const float* __restrict__ part,
                                                const float* __restrict__ bias,
                                                float* __restrict__ avg) {
    int idx = blockIdx.x * 256 + threadIdx.x;          // < 524288
    int c = idx >> 12;
    float s = 0.f;
#pragma unroll
    for (int sp = 0; sp < 8; ++sp) s += part[sp * 524288 + idx];
    avg[idx] = bias[c] + s * 0.0625f;
}

__global__ __launch_bounds__(256) void k_out(const float* __restrict__ tissue,
                                             const float* __restrict__ avg,
                                             const int* __restrict__ loc,
                                             float* __restrict__ out) {
    int idx4 = blockIdx.x * 256 + threadIdx.x;         // < 8,388,608 float4s of `final`
    size_t f = (size_t)idx4 * 4;
    int j   = idx4 >> 21;                              // sample
    int r4  = idx4 & ((1 << 21) - 1);
    int c   = r4 >> 14;
    int hw4 = r4 & 16383;
    int h   = hw4 >> 6;
    int w0  = (hw4 & 63) << 2;

    nf4 v = __builtin_nontemporal_load((const nf4*)(tissue + f));

    // axis-1 (h) uses loc[:,1]; axis-2 (w) uses loc[:,0]; start = loc/4 - 32
    int sh = (loc[2 * j + 1] >> 2) - 32;
    int sw = (loc[2 * j]     >> 2) - 32;
    int ah = h - sh;
    if (ah >= 0 && ah < 64) {
        const float* ar = avg + c * 4096 + ah * 64;
        int aw = w0 - sw;
        if (aw     >= 0 && aw     < 64) v[0] += ar[aw];
        if (aw + 1 >= 0 && aw + 1 < 64) v[1] += ar[aw + 1];
        if (aw + 2 >= 0 && aw + 2 < 64) v[2] += ar[aw + 2];
        if (aw + 3 >= 0 && aw + 3 < 64) v[3] += ar[aw + 3];
    }
#pragma unroll
    for (int b = 0; b < 4; ++b)
        __builtin_nontemporal_store(v, (nf4*)(out + (size_t)b * 33554432 + f));
}

extern "C" void kernel_launch(void* const* d_in, const int* in_sizes, int n_in,
                              void* d_out, int out_size, void* d_ws, size_t ws_size,
                              hipStream_t stream) {
    const float* tissue = (const float*)d_in[0];
    const float* cell   = (const float*)d_in[1];
    const int*   loc    = (const int*)d_in[2];
    const float* w      = (const float*)d_in[3];
    const float* bias   = (const float*)d_in[4];
    float* out = (float*)d_out;

    char* wsb = (char*)d_ws;
    float* box  = (float*)(wsb);
    float* wT2  = (float*)(wsb + 33554432);
    float* part = (float*)(wsb + 34144256);
    float* avg  = (float*)(wsb + 50921472);

    k_prep<<<6720, 256, 0, stream>>>(w, wT2, cell, box);
    k_gemm<<<dim3(64, 8), 256, 0, stream>>>(box, wT2, part);
    k_avgfin<<<2048, 256, 0, stream>>>(part, bias, avg);
    k_out<<<32768, 256, 0, stream>>>(tissue, avg, loc, out);
}

// Round 4
// 181.156 us; speedup vs baseline: 1.4054x; 1.0092x over previous
//
#include <hip/hip_runtime.h>

typedef float nf4 __attribute__((ext_vector_type(4)));

// Cell2Tissue: conv3x3(cell) -> avgpool4 -> add into per-sample ROI of tissue -> broadcast x4.
//
// Pipeline:
//  k_prep   : blocks [0,576): wT2[ci][k][c] transpose
//             blocks [576,1600): box[ci][yy][xx] = 4x4 box-sum of zero-padded cell,
//             LDS slab-staged (35 cell rows/block), rows yy%4==3 skipped.
//  k_gemm   : part[s][c][i*64+j] = sum_{ci in split s} sum_k wT2[ci][k][c]*box[ci][4i+dy][4j+dx]
//  k_avgfin : avg = bias + (sum_s part[s]) / 16
//  k_out    : out[b][j][c][h][w] = tissue[j][c][h][w] + (in ROI_j ? avg[...] : 0), b=0..3
//
// ws layout (bytes): box @0 (33,554,432) | wT2 @33,554,432 (589,824) |
//                    part @34,144,256 (16,777,216) | avg @50,921,472 (2,097,152)

#define CLS 258   // cell slab row stride (floats), +1 col halo each side
#define CSS 260   // colsum row stride (floats), 16B-aligned (260*4 = 65*16)

__global__ __launch_bounds__(256) void k_prep(const float* __restrict__ w,
                                              float* __restrict__ wT2,
                                              const float* __restrict__ cell,
                                              float* __restrict__ box) {
    if (blockIdx.x < 576) {
        int idx = blockIdx.x * 256 + threadIdx.x;      // enumerates wT2 linearly, 147456
        int c  = idx & 127;
        int k  = (idx >> 7) % 9;
        int ci = idx / (9 * 128);
        wT2[idx] = w[(c * 128 + ci) * 9 + k];
        return;
    }
    // ---- box slab: block handles (ci, s): box rows [32s, 32s+32), yy%4 != 3 (24 rows) ----
    __shared__ float cl[35 * CLS];                     // cell rows 32s-1 .. 32s+33, cols -1..256
    __shared__ float cs[24 * CSS];                     // vertical 4-sums for the 24 box rows
    int sid = blockIdx.x - 576;                        // 0..1023
    int ci = sid >> 3;
    int s  = sid & 7;
    int tid = threadIdx.x;
    int r0 = 32 * s - 1;
    const float* base = cell + (size_t)ci * 65536;

    // load 35 rows x 256 interior cols, zero OOB rows
#pragma unroll
    for (int r = 0; r < 35; ++r) {
        int gr = r0 + r;
        float val = (gr >= 0 && gr < 256) ? base[gr * 256 + tid] : 0.f;
        cl[r * CLS + 1 + tid] = val;
    }
    if (tid < 35) { cl[tid * CLS] = 0.f; cl[tid * CLS + 257] = 0.f; }
    __syncthreads();

    // stage A: cs[r24][c] = sum_{p<4} cl[lr+p][c], lr = local row of (yy-1)
    for (int q = tid; q < 24 * 258; q += 256) {
        int r24 = q / 258, c = q % 258;
        int yyl = (r24 / 3) * 4 + (r24 % 3);           // 0..30, skipping %4==3... (local yy)
        int lr = yyl;                                  // cell row (yy-1) - r0 = yy - 32s
        cs[r24 * CSS + c] = cl[lr * CLS + c] + cl[(lr + 1) * CLS + c] +
                            cl[(lr + 2) * CLS + c] + cl[(lr + 3) * CLS + c];
    }
    __syncthreads();

    // stage B: horizontal 4-sums, contiguous b128 reads
#pragma unroll
    for (int k = 0; k < 6; ++k) {
        int o = tid + 256 * k;                         // 0..1535
        int xt = o & 63;
        int r24 = o >> 6;                              // 0..23
        int yyl = (r24 / 3) * 4 + (r24 % 3);
        nf4 v0 = *(const nf4*)&cs[r24 * CSS + 4 * xt];
        nf4 v1 = *(const nf4*)&cs[r24 * CSS + 4 * xt + 4];
        float4 ov;
        ov.x = v0[0] + v0[1] + v0[2] + v0[3];
        ov.y = v0[1] + v0[2] + v0[3] + v1[0];
        ov.z = v0[2] + v0[3] + v1[0] + v1[1];
        ov.w = v0[3] + v1[0] + v1[1] + v1[2];
        *(float4*)(box + (size_t)ci * 65536 + (32 * s + yyl) * 256 + 4 * xt) = ov;
    }
}

// grid (64 rows, 8 K-splits), 256 threads. Lane = channel group (4 c), pg = 8 positions.
// All weight reads: coalesced global -> LDS -> ds_read_b128 (no scalar-promotion reliance).
// All box reads: LDS broadcast (same addr across half-wave) -> free.
__global__ __launch_bounds__(256) void k_gemm(const float* __restrict__ box,
                                              const float* __restrict__ wT2,
                                              float* __restrict__ part) {
    __shared__ float wlds[2][1152];                    // [buf][k*128 + c]
    __shared__ float boxlds[2][768];                   // [buf][dy*256 + x]
    int i     = blockIdx.x;                            // pooled row 0..63
    int split = blockIdx.y;                            // 0..7
    int tid = threadIdx.x;
    int cg  = tid & 31;                                // c = 4*cg .. 4*cg+3
    int pg  = tid >> 5;                                // j = 8*pg .. 8*pg+7

    float acc[4][8];
#pragma unroll
    for (int a = 0; a < 4; ++a)
#pragma unroll
        for (int p = 0; p < 8; ++p) acc[a][p] = 0.f;

    int ci0 = split * 16;

    auto stage = [&](int ci, int buf) {
        const float* bsrc = box + (size_t)ci * 65536 + (4 * i) * 256;  // rows 4i..4i+2
#pragma unroll
        for (int s = 0; s < 3; ++s)
            boxlds[buf][tid + 256 * s] = bsrc[tid + 256 * s];
        const float* wsrc = wT2 + (size_t)ci * 1152;
#pragma unroll
        for (int s = 0; s < 5; ++s) {
            int q = tid + 256 * s;
            if (q < 1152) wlds[buf][q] = wsrc[q];
        }
    };

    stage(ci0, 0);
    for (int t = 0; t < 16; ++t) {
        __syncthreads();
        if (t < 15) stage(ci0 + t + 1, (t + 1) & 1);
        int b = t & 1;

        nf4 wv[9];
#pragma unroll
        for (int k = 0; k < 9; ++k)
            wv[k] = *(const nf4*)&wlds[b][k * 128 + 4 * cg];

#pragma unroll
        for (int p = 0; p < 8; ++p) {
            int j = 8 * pg + p;
            nf4 b0 = *(const nf4*)&boxlds[b][0 * 256 + 4 * j];
            nf4 b1 = *(const nf4*)&boxlds[b][1 * 256 + 4 * j];
            nf4 b2 = *(const nf4*)&boxlds[b][2 * 256 + 4 * j];
#pragma unroll
            for (int a = 0; a < 4; ++a) {
                float sm = acc[a][p];
                sm = fmaf(wv[0][a], b0[0], sm);
                sm = fmaf(wv[1][a], b0[1], sm);
                sm = fmaf(wv[2][a], b0[2], sm);
                sm = fmaf(wv[3][a], b1[0], sm);
                sm = fmaf(wv[4][a], b1[1], sm);
                sm = fmaf(wv[5][a], b1[2], sm);
                sm = fmaf(wv[6][a], b2[0], sm);
                sm = fmaf(wv[7][a], b2[1], sm);
                sm = fmaf(wv[8][a], b2[2], sm);
                acc[a][p] = sm;
            }
        }
    }

    float* dst = part + (size_t)split * (128 * 4096);
#pragma unroll
    for (int a = 0; a < 4; ++a) {
        int c = 4 * cg + a;
        float* row = dst + (size_t)c * 4096 + i * 64 + 8 * pg;
        float4 lo = make_float4(acc[a][0], acc[a][1], acc[a][2], acc[a][3]);
        float4 hi = make_float4(acc[a][4], acc[a][5], acc[a][6], acc[a][7]);
        *(float4*)(row)     = lo;
        *(float4*)(row + 4) = hi;
    }
}

__global__ __launch_bounds__(256) void k_avgfin(const float* __restrict__ part,
                                                const float* __restrict__ bias,
                                                float* __restrict__ avg) {
    int idx4 = blockIdx.x * 256 + threadIdx.x;         // < 131072 float4s
    int c = idx4 >> 10;
    nf4 s = {0.f, 0.f, 0.f, 0.f};
#pragma unroll
    for (int sp = 0; sp < 8; ++sp) {
        nf4 v = *(const nf4*)(part + (size_t)sp * 524288 + (size_t)idx4 * 4);
        s += v;
    }
    float b = bias[c];
    nf4 o = s * 0.0625f + b;
    *(nf4*)(avg + (size_t)idx4 * 4) = o;
}

__global__ __launch_bounds__(256) void k_out(const float* __restrict__ tissue,
                                             const float* __restrict__ avg,
                                             const int* __restrict__ loc,
                                             float* __restrict__ out) {
    int idx4 = blockIdx.x * 256 + threadIdx.x;         // < 8,388,608 float4s of `final`
    size_t f = (size_t)idx4 * 4;
    int j   = idx4 >> 21;                              // sample
    int r4  = idx4 & ((1 << 21) - 1);
    int c   = r4 >> 14;
    int hw4 = r4 & 16383;
    int h   = hw4 >> 6;
    int w0  = (hw4 & 63) << 2;

    nf4 v = __builtin_nontemporal_load((const nf4*)(tissue + f));

    // axis-1 (h) uses loc[:,1]; axis-2 (w) uses loc[:,0]; start = loc/4 - 32
    int sh = (loc[2 * j + 1] >> 2) - 32;
    int sw = (loc[2 * j]     >> 2) - 32;
    int ah = h - sh;
    if (ah >= 0 && ah < 64) {
        const float* ar = avg + c * 4096 + ah * 64;
        int aw = w0 - sw;
        if (aw     >= 0 && aw     < 64) v[0] += ar[aw];
        if (aw + 1 >= 0 && aw + 1 < 64) v[1] += ar[aw + 1];
        if (aw + 2 >= 0 && aw + 2 < 64) v[2] += ar[aw + 2];
        if (aw + 3 >= 0 && aw + 3 < 64) v[3] += ar[aw + 3];
    }
#pragma unroll
    for (int b = 0; b < 4; ++b)
        __builtin_nontemporal_store(v, (nf4*)(out + (size_t)b * 33554432 + f));
}

extern "C" void kernel_launch(void* const* d_in, const int* in_sizes, int n_in,
                              void* d_out, int out_size, void* d_ws, size_t ws_size,
                              hipStream_t stream) {
    const float* tissue = (const float*)d_in[0];
    const float* cell   = (const float*)d_in[1];
    const int*   loc    = (const int*)d_in[2];
    const float* w      = (const float*)d_in[3];
    const float* bias   = (const float*)d_in[4];
    float* out = (float*)d_out;

    char* wsb = (char*)d_ws;
    float* box  = (float*)(wsb);
    float* wT2  = (float*)(wsb + 33554432);
    float* part = (float*)(wsb + 34144256);
    float* avg  = (float*)(wsb + 50921472);

    k_prep<<<1600, 256, 0, stream>>>(w, wT2, cell, box);
    k_gemm<<<dim3(64, 8), 256, 0, stream>>>(box, wT2, part);
    k_avgfin<<<512, 256, 0, stream>>>(part, bias, avg);
    k_out<<<32768, 256, 0, stream>>>(tissue, avg, loc, out);
}